// Round 3
// baseline (594.603 us; speedup 1.0000x reference)
//
#include <hip/hip_runtime.h>
#include <stdint.h>

#define BATCH 8
#define NLEAF 64
#define VOCAB 128000
#define ROW (NLEAF * VOCAB)        // 8,192,000
#define CHUNK 4096
#define NCHUNK (ROW / CHUNK)       // 2000 (exact)
#define TOPK 64

// ---------------------------------------------------------------------------
// Kernel 1: per-chunk max of product. One block = one 4096-elem chunk.
// A chunk spans at most 2 leaves (CHUNK < VOCAB); VOCAB%4==0 so a float4
// never straddles a leaf boundary. This is the mandatory 262MB read.
// ---------------------------------------------------------------------------
__global__ __launch_bounds__(256) void k_chunkmax(
    const float* __restrict__ sp, const float* __restrict__ pp,
    float* __restrict__ cmax)
{
    int c   = blockIdx.x;            // 0 .. BATCH*NCHUNK-1
    int row = c / NCHUNK;
    int cr  = c - row * NCHUNK;
    long base = (long)row * ROW + (long)cr * CHUNK;
    int fr    = cr * CHUNK;          // row-local flat base
    int leaf0 = fr / VOCAB;
    int bnd   = (leaf0 + 1) * VOCAB; // row-local leaf boundary (multiple of 4)
    float p0  = pp[row * NLEAF + leaf0];
    float p1  = (leaf0 + 1 < NLEAF) ? pp[row * NLEAF + leaf0 + 1] : 0.f;

    int t = threadIdx.x;
    const float4* sp4 = (const float4*)(sp + base);
    float m = 0.f;                   // products are >= 0
#pragma unroll
    for (int i = 0; i < 4; ++i) {
        int e4 = t + i * 256;        // float4 index within chunk
        float4 v = sp4[e4];
        float p = ((fr + e4 * 4) < bnd) ? p0 : p1;
        m = fmaxf(m, fmaxf(fmaxf(v.x * p, v.y * p), fmaxf(v.z * p, v.w * p)));
    }
    for (int off = 32; off; off >>= 1) m = fmaxf(m, __shfl_down(m, off, 64));
    __shared__ float s[4];
    if ((t & 63) == 0) s[t >> 6] = m;
    __syncthreads();
    if (t == 0) cmax[c] = fmaxf(fmaxf(s[0], s[1]), fmaxf(s[2], s[3]));
}

// ---------------------------------------------------------------------------
// Kernel 2: per row, EXACT 64th-largest chunk max via 4-level radix select
// on the float bits (values >= 0 so uint order == float order).
// Also zeroes the candidate counter.
// ---------------------------------------------------------------------------
__global__ __launch_bounds__(256) void k_threshold(
    const float* __restrict__ cmax, float* __restrict__ thr,
    int* __restrict__ cnt)
{
    int row = blockIdx.x;
    int t = threadIdx.x;
    __shared__ unsigned uv[NCHUNK];
    __shared__ int hist[256], sc[256];
    __shared__ unsigned s_prefix;
    __shared__ int s_k;
    for (int i = t; i < NCHUNK; i += 256)
        uv[i] = __float_as_uint(cmax[row * NCHUNK + i]);
    if (t == 0) { cnt[row] = 0; s_prefix = 0u; s_k = TOPK; }
    __syncthreads();

    for (int level = 3; level >= 0; --level) {
        int shift = level * 8;
        hist[t] = 0;
        __syncthreads();
        unsigned prefix = s_prefix; int kk = s_k;
        for (int i = t; i < NCHUNK; i += 256) {
            unsigned u = uv[i];
            bool mm = (level == 3) || ((u >> (shift + 8)) == prefix);
            unsigned bin = mm ? ((u >> shift) & 255u) : 0xFFFFFFFFu;
            // wave-uniform fast path (degenerate levels: all keys same byte)
            unsigned fb = __builtin_amdgcn_readfirstlane(bin);
            unsigned long long bal = __ballot(bin == fb);
            if (bal == ~0ull) {
                if ((t & 63) == 0 && fb != 0xFFFFFFFFu) atomicAdd(&hist[fb], 64);
            } else if (bin != 0xFFFFFFFFu) {
                atomicAdd(&hist[bin], 1);
            }
        }
        __syncthreads();
        sc[t] = hist[t];
        __syncthreads();
        for (int off = 1; off < 256; off <<= 1) {
            int v = sc[t];
            if (t + off < 256) v += sc[t + off];
            __syncthreads();
            sc[t] = v;
            __syncthreads();
        }
        int gt = (t < 255) ? sc[t + 1] : 0;   // count of keys strictly above bin t
        if (gt < kk && kk <= gt + hist[t]) {
            s_prefix = (prefix << 8) | (unsigned)t;
            s_k = kk - gt;
        }
        __syncthreads();
    }
    if (t == 0) thr[row] = __uint_as_float(s_prefix);
}

// ---------------------------------------------------------------------------
// Kernel 3: collect candidates >= threshold with ONE atomic per block
// (block prefix-sum over per-thread match counts). ~99.4% of blocks exit
// after two scalar loads.
// ---------------------------------------------------------------------------
__global__ __launch_bounds__(256) void k_collect(
    const float* __restrict__ sp, const float* __restrict__ pp,
    const float* __restrict__ cmax, const float* __restrict__ thr,
    int* __restrict__ cnt, unsigned long long* __restrict__ cand, int cap)
{
    int c   = blockIdx.x;
    int row = c / NCHUNK;
    float tval = thr[row];
    if (cmax[c] < tval) return;   // block-uniform exit

    int cr = c - row * NCHUNK;
    long base = (long)row * ROW + (long)cr * CHUNK;
    int fr    = cr * CHUNK;
    int leaf0 = fr / VOCAB;
    int bnd   = (leaf0 + 1) * VOCAB;
    float p0  = pp[row * NLEAF + leaf0];
    float p1  = (leaf0 + 1 < NLEAF) ? pp[row * NLEAF + leaf0 + 1] : 0.f;

    int t = threadIdx.x;
    const float4* sp4 = (const float4*)(sp + base);
    float pr[16];
    int m = 0;
#pragma unroll
    for (int i = 0; i < 4; ++i) {
        int e4 = t + i * 256;
        float4 v = sp4[e4];
        float p = ((fr + e4 * 4) < bnd) ? p0 : p1;
        pr[i * 4 + 0] = v.x * p;
        pr[i * 4 + 1] = v.y * p;
        pr[i * 4 + 2] = v.z * p;
        pr[i * 4 + 3] = v.w * p;
#pragma unroll
        for (int j = 0; j < 4; ++j) m += (pr[i * 4 + j] >= tval) ? 1 : 0;
    }

    __shared__ int sc2[256];
    __shared__ int sbase;
    sc2[t] = m;
    __syncthreads();
    for (int off = 1; off < 256; off <<= 1) {       // inclusive Hillis-Steele
        int v = sc2[t];
        if (t >= off) v += sc2[t - off];
        __syncthreads();
        sc2[t] = v;
        __syncthreads();
    }
    if (t == 255) sbase = atomicAdd(&cnt[row], sc2[255]);
    __syncthreads();

    if (m > 0) {
        int pos = sbase + sc2[t] - m;
#pragma unroll
        for (int i = 0; i < 4; ++i) {
#pragma unroll
            for (int j = 0; j < 4; ++j) {
                float v = pr[i * 4 + j];
                if (v >= tval) {
                    if (pos < cap) {
                        unsigned fb = __float_as_uint(v);
                        unsigned fi = (unsigned)(fr + (t + i * 256) * 4 + j);
                        cand[(long)row * cap + pos] =
                            ((unsigned long long)fb << 32) |
                            (unsigned long long)(0xFFFFFFFFu - fi);
                    }
                    pos++;
                }
            }
        }
    }
}

// ---------------------------------------------------------------------------
// Kernel 4: per row, exact top-64 of the candidate keys.
// Fast path (nc <= 2048): LDS rank-sort — keys unique (distinct fi), so
// rank = #greater keys; write ranks < 64 directly.
// Fallback: proven 8-level radix select (identical to baseline).
// ---------------------------------------------------------------------------
__global__ __launch_bounds__(256) void k_final(
    const int* __restrict__ cnt, const unsigned long long* __restrict__ cand,
    int cap, float* __restrict__ out)
{
    int row = blockIdx.x;
    int t = threadIdx.x;
    int nc = cnt[row]; if (nc > cap) nc = cap;
    const unsigned long long* c = cand + (long)row * cap;

    if (nc <= 2048) {
        __shared__ unsigned long long keys[2048];
        for (int i = t; i < nc; i += 256) keys[i] = c[i];
        __syncthreads();
        for (int i = t; i < nc; i += 256) {
            unsigned long long k = keys[i];
            int rank = 0;
            for (int jj = 0; jj < nc; ++jj) rank += (keys[jj] > k) ? 1 : 0;
            if (rank < TOPK) {
                unsigned fi = 0xFFFFFFFFu - (unsigned)(k & 0xFFFFFFFFull);
                float val = __uint_as_float((unsigned)(k >> 32));
                int tok  = (int)(fi % VOCAB);
                int leaf = (int)(fi / VOCAB);
                out[row * TOPK + rank]                    = (float)tok;
                out[BATCH * TOPK + row * TOPK + rank]     = val;
                out[2 * BATCH * TOPK + row * TOPK + rank] = (float)leaf;
            }
        }
        return;
    }

    // ---- fallback: 8-level radix select over 64-bit keys ----
    __shared__ int hist[256], sc[256];
    __shared__ unsigned long long s_prefix;
    __shared__ int s_k;
    __shared__ unsigned long long stop[TOPK];
    __shared__ int s_ntop;
    if (t == 0) { s_prefix = 0ull; s_k = TOPK; s_ntop = 0; }
    __syncthreads();

    for (int level = 7; level >= 0; --level) {
        int shift = level * 8;
        hist[t] = 0;
        __syncthreads();
        unsigned long long prefix = s_prefix; int kk = s_k;
        for (int i = t; i < nc; i += 256) {
            unsigned long long u = c[i];
            bool mm = (level == 7) || ((u >> (shift + 8)) == prefix);
            unsigned bin = mm ? (unsigned)((u >> shift) & 255ull) : 0xFFFFFFFFu;
            unsigned fb = __builtin_amdgcn_readfirstlane(bin);
            unsigned long long bal = __ballot(bin == fb);
            if (bal == ~0ull) {
                if ((t & 63) == 0 && fb != 0xFFFFFFFFu) atomicAdd(&hist[fb], 64);
            } else if (bin != 0xFFFFFFFFu) {
                atomicAdd(&hist[bin], 1);
            }
        }
        __syncthreads();
        sc[t] = hist[t];
        __syncthreads();
        for (int off = 1; off < 256; off <<= 1) {
            int v = sc[t];
            if (t + off < 256) v += sc[t + off];
            __syncthreads();
            sc[t] = v;
            __syncthreads();
        }
        int gt = (t < 255) ? sc[t + 1] : 0;
        if (gt < kk && kk <= gt + hist[t]) {
            s_prefix = (prefix << 8) | (unsigned long long)t;
            s_k = kk - gt;
        }
        __syncthreads();
    }

    unsigned long long K64 = s_prefix;   // exact 64th-largest key
    for (int i = t; i < nc; i += 256) {
        unsigned long long u = c[i];
        if (u >= K64) {
            int p = atomicAdd(&s_ntop, 1);
            if (p < TOPK) stop[p] = u;
        }
    }
    __syncthreads();

    int ntop = s_ntop; if (ntop > TOPK) ntop = TOPK;
    if (t < ntop) {
        unsigned long long mykey = stop[t];
        int rank = 0;
        for (int j = 0; j < ntop; ++j) rank += (stop[j] > mykey) ? 1 : 0;
        unsigned fi = 0xFFFFFFFFu - (unsigned)(mykey & 0xFFFFFFFFull);
        float val = __uint_as_float((unsigned)(mykey >> 32));
        int tok  = (int)(fi % VOCAB);
        int leaf = (int)(fi / VOCAB);
        out[row * TOPK + rank]                    = (float)tok;
        out[BATCH * TOPK + row * TOPK + rank]     = val;
        out[2 * BATCH * TOPK + row * TOPK + rank] = (float)leaf;
    }
}

extern "C" void kernel_launch(void* const* d_in, const int* in_sizes, int n_in,
                              void* d_out, int out_size, void* d_ws, size_t ws_size,
                              hipStream_t stream) {
    const float* sp = (const float*)d_in[0];   // [8,64,128000] f32
    const float* pp = (const float*)d_in[1];   // [8,64] f32
    float* out = (float*)d_out;                // 1536 f32

    char* ws = (char*)d_ws;
    float* cmax = (float*)ws;                              // 16000 f32
    float* thr  = (float*)(ws + 64000);                    // 8 f32
    int*   cnt  = (int*)(ws + 64032);                      // 8 i32
    unsigned long long* cand = (unsigned long long*)(ws + 65536);

    int cap = 16384;
    size_t need = 65536 + (size_t)BATCH * (size_t)cap * 8;
    if (ws_size < need) {
        cap = (int)((ws_size > 65536 ? (ws_size - 65536) : 0) / (BATCH * 8));
        if (cap < 256) cap = 256;
    }

    k_chunkmax <<<BATCH * NCHUNK, 256, 0, stream>>>(sp, pp, cmax);
    k_threshold<<<BATCH,          256, 0, stream>>>(cmax, thr, cnt);
    k_collect  <<<BATCH * NCHUNK, 256, 0, stream>>>(sp, pp, cmax, thr, cnt, cand, cap);
    k_final    <<<BATCH,          256, 0, stream>>>(cnt, cand, cap, out);
}

// Round 4
// 460.434 us; speedup vs baseline: 1.2914x; 1.2914x over previous
//
#include <hip/hip_runtime.h>
#include <stdint.h>

#define BATCH 8
#define NLEAF 64
#define VOCAB 128000
#define ROW (NLEAF * VOCAB)        // 8,192,000
#define CHUNK 4096
#define NCHUNK (ROW / CHUNK)       // 2000 (exact)
#define TOPK 64

// ---------------------------------------------------------------------------
// Kernel 1: per-chunk max of product. One block = one 4096-elem chunk.
// A chunk spans at most 2 leaves (CHUNK < VOCAB); VOCAB%4==0 so a float4
// never straddles a leaf boundary. This is the mandatory 262MB read.
// ---------------------------------------------------------------------------
__global__ __launch_bounds__(256) void k_chunkmax(
    const float* __restrict__ sp, const float* __restrict__ pp,
    float* __restrict__ cmax)
{
    int c   = blockIdx.x;            // 0 .. BATCH*NCHUNK-1
    int row = c / NCHUNK;
    int cr  = c - row * NCHUNK;
    long base = (long)row * ROW + (long)cr * CHUNK;
    int fr    = cr * CHUNK;          // row-local flat base
    int leaf0 = fr / VOCAB;
    int bnd   = (leaf0 + 1) * VOCAB; // row-local leaf boundary (multiple of 4)
    float p0  = pp[row * NLEAF + leaf0];
    float p1  = (leaf0 + 1 < NLEAF) ? pp[row * NLEAF + leaf0 + 1] : 0.f;

    int t = threadIdx.x;
    const float4* sp4 = (const float4*)(sp + base);
    float m = 0.f;                   // products are >= 0
#pragma unroll
    for (int i = 0; i < 4; ++i) {
        int e4 = t + i * 256;        // float4 index within chunk
        float4 v = sp4[e4];
        float p = ((fr + e4 * 4) < bnd) ? p0 : p1;
        m = fmaxf(m, fmaxf(fmaxf(v.x * p, v.y * p), fmaxf(v.z * p, v.w * p)));
    }
    for (int off = 32; off; off >>= 1) m = fmaxf(m, __shfl_down(m, off, 64));
    __shared__ float s[4];
    if ((t & 63) == 0) s[t >> 6] = m;
    __syncthreads();
    if (t == 0) cmax[c] = fmaxf(fmaxf(s[0], s[1]), fmaxf(s[2], s[3]));
}

// ---------------------------------------------------------------------------
// Kernel 2: per row, EXACT 64th-largest chunk max via 4-level radix select
// on the float bits (values >= 0 so uint order == float order).
// Also zeroes the candidate counter.
// ---------------------------------------------------------------------------
__global__ __launch_bounds__(256) void k_threshold(
    const float* __restrict__ cmax, float* __restrict__ thr,
    int* __restrict__ cnt)
{
    int row = blockIdx.x;
    int t = threadIdx.x;
    __shared__ unsigned uv[NCHUNK];
    __shared__ int hist[256], sc[256];
    __shared__ unsigned s_prefix;
    __shared__ int s_k;
    for (int i = t; i < NCHUNK; i += 256)
        uv[i] = __float_as_uint(cmax[row * NCHUNK + i]);
    if (t == 0) { cnt[row] = 0; s_prefix = 0u; s_k = TOPK; }
    __syncthreads();

    for (int level = 3; level >= 0; --level) {
        int shift = level * 8;
        hist[t] = 0;
        __syncthreads();
        unsigned prefix = s_prefix; int kk = s_k;
        for (int i = t; i < NCHUNK; i += 256) {
            unsigned u = uv[i];
            bool mm = (level == 3) || ((u >> (shift + 8)) == prefix);
            unsigned bin = mm ? ((u >> shift) & 255u) : 0xFFFFFFFFu;
            // wave-uniform fast path (degenerate levels: all keys same byte)
            unsigned fb = __builtin_amdgcn_readfirstlane(bin);
            unsigned long long bal = __ballot(bin == fb);
            if (bal == ~0ull) {
                if ((t & 63) == 0 && fb != 0xFFFFFFFFu) atomicAdd(&hist[fb], 64);
            } else if (bin != 0xFFFFFFFFu) {
                atomicAdd(&hist[bin], 1);
            }
        }
        __syncthreads();
        sc[t] = hist[t];
        __syncthreads();
        for (int off = 1; off < 256; off <<= 1) {
            int v = sc[t];
            if (t + off < 256) v += sc[t + off];
            __syncthreads();
            sc[t] = v;
            __syncthreads();
        }
        int gt = (t < 255) ? sc[t + 1] : 0;   // count of keys strictly above bin t
        if (gt < kk && kk <= gt + hist[t]) {
            s_prefix = (prefix << 8) | (unsigned)t;
            s_k = kk - gt;
        }
        __syncthreads();
    }
    if (t == 0) thr[row] = __uint_as_float(s_prefix);
}

// ---------------------------------------------------------------------------
// Kernel 3: collect candidates >= threshold with ONE atomic per block
// (block prefix-sum over per-thread match counts). ~99.4% of blocks exit
// after two scalar loads.
// ---------------------------------------------------------------------------
__global__ __launch_bounds__(256) void k_collect(
    const float* __restrict__ sp, const float* __restrict__ pp,
    const float* __restrict__ cmax, const float* __restrict__ thr,
    int* __restrict__ cnt, unsigned long long* __restrict__ cand, int cap)
{
    int c   = blockIdx.x;
    int row = c / NCHUNK;
    float tval = thr[row];
    if (cmax[c] < tval) return;   // block-uniform exit

    int cr = c - row * NCHUNK;
    long base = (long)row * ROW + (long)cr * CHUNK;
    int fr    = cr * CHUNK;
    int leaf0 = fr / VOCAB;
    int bnd   = (leaf0 + 1) * VOCAB;
    float p0  = pp[row * NLEAF + leaf0];
    float p1  = (leaf0 + 1 < NLEAF) ? pp[row * NLEAF + leaf0 + 1] : 0.f;

    int t = threadIdx.x;
    const float4* sp4 = (const float4*)(sp + base);
    float pr[16];
    int m = 0;
#pragma unroll
    for (int i = 0; i < 4; ++i) {
        int e4 = t + i * 256;
        float4 v = sp4[e4];
        float p = ((fr + e4 * 4) < bnd) ? p0 : p1;
        pr[i * 4 + 0] = v.x * p;
        pr[i * 4 + 1] = v.y * p;
        pr[i * 4 + 2] = v.z * p;
        pr[i * 4 + 3] = v.w * p;
#pragma unroll
        for (int j = 0; j < 4; ++j) m += (pr[i * 4 + j] >= tval) ? 1 : 0;
    }

    __shared__ int sc2[256];
    __shared__ int sbase;
    sc2[t] = m;
    __syncthreads();
    for (int off = 1; off < 256; off <<= 1) {       // inclusive Hillis-Steele
        int v = sc2[t];
        if (t >= off) v += sc2[t - off];
        __syncthreads();
        sc2[t] = v;
        __syncthreads();
    }
    if (t == 255) sbase = atomicAdd(&cnt[row], sc2[255]);
    __syncthreads();

    if (m > 0) {
        int pos = sbase + sc2[t] - m;
#pragma unroll
        for (int i = 0; i < 4; ++i) {
#pragma unroll
            for (int j = 0; j < 4; ++j) {
                float v = pr[i * 4 + j];
                if (v >= tval) {
                    if (pos < cap) {
                        unsigned fb = __float_as_uint(v);
                        unsigned fi = (unsigned)(fr + (t + i * 256) * 4 + j);
                        cand[(long)row * cap + pos] =
                            ((unsigned long long)fb << 32) |
                            (unsigned long long)(0xFFFFFFFFu - fi);
                    }
                    pos++;
                }
            }
        }
    }
}

// ---------------------------------------------------------------------------
// Kernel 4: per row, exact top-64 of the candidate keys.
// Fast path (nc <= 2048; measured nc ~= 1100): register-tiled rank-sort.
// Each thread caches its <=8 keys in REGISTERS, then ONE pass over all keys
// in LDS (independent broadcast reads, unrollable) updates 8 rank counters
// with compile-time indices. Keys unique -> rank = #greater; ranks < 64 win.
// Fallback: proven 8-level radix select (unchanged).
// ---------------------------------------------------------------------------
__global__ __launch_bounds__(256) void k_final(
    const int* __restrict__ cnt, const unsigned long long* __restrict__ cand,
    int cap, float* __restrict__ out)
{
    int row = blockIdx.x;
    int t = threadIdx.x;
    int nc = cnt[row]; if (nc > cap) nc = cap;
    const unsigned long long* c = cand + (long)row * cap;

    if (nc <= 2048) {
        __shared__ unsigned long long keys[2048];
        for (int i = t; i < nc; i += 256) keys[i] = c[i];
        __syncthreads();

        unsigned long long my[8];
        int rank[8];
        int nmine = 0;
#pragma unroll
        for (int q = 0; q < 8; ++q) {
            int i = t + q * 256;
            if (i < nc) { my[q] = keys[i]; rank[q] = 0; nmine = q + 1; }
            else        { my[q] = ~0ull;  rank[q] = TOPK; }
        }
        for (int jj = 0; jj < nc; ++jj) {
            unsigned long long kj = keys[jj];
#pragma unroll
            for (int q = 0; q < 8; ++q)
                rank[q] += (kj > my[q]) ? 1 : 0;
        }
#pragma unroll
        for (int q = 0; q < 8; ++q) {
            if (q < nmine && rank[q] < TOPK) {
                unsigned long long k = my[q];
                unsigned fi = 0xFFFFFFFFu - (unsigned)(k & 0xFFFFFFFFull);
                float val = __uint_as_float((unsigned)(k >> 32));
                int tok  = (int)(fi % VOCAB);
                int leaf = (int)(fi / VOCAB);
                int r = rank[q];
                out[row * TOPK + r]                    = (float)tok;
                out[BATCH * TOPK + row * TOPK + r]     = val;
                out[2 * BATCH * TOPK + row * TOPK + r] = (float)leaf;
            }
        }
        return;
    }

    // ---- fallback: 8-level radix select over 64-bit keys ----
    __shared__ int hist[256], sc[256];
    __shared__ unsigned long long s_prefix;
    __shared__ int s_k;
    __shared__ unsigned long long stop[TOPK];
    __shared__ int s_ntop;
    if (t == 0) { s_prefix = 0ull; s_k = TOPK; s_ntop = 0; }
    __syncthreads();

    for (int level = 7; level >= 0; --level) {
        int shift = level * 8;
        hist[t] = 0;
        __syncthreads();
        unsigned long long prefix = s_prefix; int kk = s_k;
        for (int i = t; i < nc; i += 256) {
            unsigned long long u = c[i];
            bool mm = (level == 7) || ((u >> (shift + 8)) == prefix);
            unsigned bin = mm ? (unsigned)((u >> shift) & 255ull) : 0xFFFFFFFFu;
            unsigned fb = __builtin_amdgcn_readfirstlane(bin);
            unsigned long long bal = __ballot(bin == fb);
            if (bal == ~0ull) {
                if ((t & 63) == 0 && fb != 0xFFFFFFFFu) atomicAdd(&hist[fb], 64);
            } else if (bin != 0xFFFFFFFFu) {
                atomicAdd(&hist[bin], 1);
            }
        }
        __syncthreads();
        sc[t] = hist[t];
        __syncthreads();
        for (int off = 1; off < 256; off <<= 1) {
            int v = sc[t];
            if (t + off < 256) v += sc[t + off];
            __syncthreads();
            sc[t] = v;
            __syncthreads();
        }
        int gt = (t < 255) ? sc[t + 1] : 0;
        if (gt < kk && kk <= gt + hist[t]) {
            s_prefix = (prefix << 8) | (unsigned long long)t;
            s_k = kk - gt;
        }
        __syncthreads();
    }

    unsigned long long K64 = s_prefix;   // exact 64th-largest key
    for (int i = t; i < nc; i += 256) {
        unsigned long long u = c[i];
        if (u >= K64) {
            int p = atomicAdd(&s_ntop, 1);
            if (p < TOPK) stop[p] = u;
        }
    }
    __syncthreads();

    int ntop = s_ntop; if (ntop > TOPK) ntop = TOPK;
    if (t < ntop) {
        unsigned long long mykey = stop[t];
        int rank = 0;
        for (int j = 0; j < ntop; ++j) rank += (stop[j] > mykey) ? 1 : 0;
        unsigned fi = 0xFFFFFFFFu - (unsigned)(mykey & 0xFFFFFFFFull);
        float val = __uint_as_float((unsigned)(mykey >> 32));
        int tok  = (int)(fi % VOCAB);
        int leaf = (int)(fi / VOCAB);
        out[row * TOPK + rank]                    = (float)tok;
        out[BATCH * TOPK + row * TOPK + rank]     = val;
        out[2 * BATCH * TOPK + row * TOPK + rank] = (float)leaf;
    }
}

extern "C" void kernel_launch(void* const* d_in, const int* in_sizes, int n_in,
                              void* d_out, int out_size, void* d_ws, size_t ws_size,
                              hipStream_t stream) {
    const float* sp = (const float*)d_in[0];   // [8,64,128000] f32
    const float* pp = (const float*)d_in[1];   // [8,64] f32
    float* out = (float*)d_out;                // 1536 f32

    char* ws = (char*)d_ws;
    float* cmax = (float*)ws;                              // 16000 f32
    float* thr  = (float*)(ws + 64000);                    // 8 f32
    int*   cnt  = (int*)(ws + 64032);                      // 8 i32
    unsigned long long* cand = (unsigned long long*)(ws + 65536);

    int cap = 16384;
    size_t need = 65536 + (size_t)BATCH * (size_t)cap * 8;
    if (ws_size < need) {
        cap = (int)((ws_size > 65536 ? (ws_size - 65536) : 0) / (BATCH * 8));
        if (cap < 256) cap = 256;
    }

    k_chunkmax <<<BATCH * NCHUNK, 256, 0, stream>>>(sp, pp, cmax);
    k_threshold<<<BATCH,          256, 0, stream>>>(cmax, thr, cnt);
    k_collect  <<<BATCH * NCHUNK, 256, 0, stream>>>(sp, pp, cmax, thr, cnt, cand, cap);
    k_final    <<<BATCH,          256, 0, stream>>>(cnt, cand, cap, out);
}

// Round 5
// 435.119 us; speedup vs baseline: 1.3665x; 1.0582x over previous
//
#include <hip/hip_runtime.h>
#include <stdint.h>

#define BATCH 8
#define NLEAF 64
#define VOCAB 128000
#define ROW (NLEAF * VOCAB)        // 8,192,000
#define CHUNK 4096
#define NCHUNK (ROW / CHUNK)       // 2000 (exact)
#define TOPK 64

// ---------------------------------------------------------------------------
// Kernel 1: per-chunk max of product. One block = one 4096-elem chunk.
// A chunk spans at most 2 leaves (CHUNK < VOCAB); VOCAB%4==0 so a float4
// never straddles a leaf boundary. This is the mandatory 262MB read.
// ---------------------------------------------------------------------------
__global__ __launch_bounds__(256) void k_chunkmax(
    const float* __restrict__ sp, const float* __restrict__ pp,
    float* __restrict__ cmax)
{
    int c   = blockIdx.x;            // 0 .. BATCH*NCHUNK-1
    int row = c / NCHUNK;
    int cr  = c - row * NCHUNK;
    long base = (long)row * ROW + (long)cr * CHUNK;
    int fr    = cr * CHUNK;          // row-local flat base
    int leaf0 = fr / VOCAB;
    int bnd   = (leaf0 + 1) * VOCAB; // row-local leaf boundary (multiple of 4)
    float p0  = pp[row * NLEAF + leaf0];
    float p1  = (leaf0 + 1 < NLEAF) ? pp[row * NLEAF + leaf0 + 1] : 0.f;

    int t = threadIdx.x;
    const float4* sp4 = (const float4*)(sp + base);
    float m = 0.f;                   // products are >= 0
#pragma unroll
    for (int i = 0; i < 4; ++i) {
        int e4 = t + i * 256;        // float4 index within chunk
        float4 v = sp4[e4];
        float p = ((fr + e4 * 4) < bnd) ? p0 : p1;
        m = fmaxf(m, fmaxf(fmaxf(v.x * p, v.y * p), fmaxf(v.z * p, v.w * p)));
    }
    for (int off = 32; off; off >>= 1) m = fmaxf(m, __shfl_down(m, off, 64));
    __shared__ float s[4];
    if ((t & 63) == 0) s[t >> 6] = m;
    __syncthreads();
    if (t == 0) cmax[c] = fmaxf(fmaxf(s[0], s[1]), fmaxf(s[2], s[3]));
}

// ---------------------------------------------------------------------------
// Kernel 2: per row, EXACT 64th-largest chunk max via 4-level radix select
// on the float bits (values >= 0 so uint order == float order).
// Also zeroes the candidate counter.
// ---------------------------------------------------------------------------
__global__ __launch_bounds__(256) void k_threshold(
    const float* __restrict__ cmax, float* __restrict__ thr,
    int* __restrict__ cnt)
{
    int row = blockIdx.x;
    int t = threadIdx.x;
    __shared__ unsigned uv[NCHUNK];
    __shared__ int hist[256], sc[256];
    __shared__ unsigned s_prefix;
    __shared__ int s_k;
    for (int i = t; i < NCHUNK; i += 256)
        uv[i] = __float_as_uint(cmax[row * NCHUNK + i]);
    if (t == 0) { cnt[row] = 0; s_prefix = 0u; s_k = TOPK; }
    __syncthreads();

    for (int level = 3; level >= 0; --level) {
        int shift = level * 8;
        hist[t] = 0;
        __syncthreads();
        unsigned prefix = s_prefix; int kk = s_k;
        for (int i = t; i < NCHUNK; i += 256) {
            unsigned u = uv[i];
            bool mm = (level == 3) || ((u >> (shift + 8)) == prefix);
            unsigned bin = mm ? ((u >> shift) & 255u) : 0xFFFFFFFFu;
            // wave-uniform fast path (degenerate levels: all keys same byte)
            unsigned fb = __builtin_amdgcn_readfirstlane(bin);
            unsigned long long bal = __ballot(bin == fb);
            if (bal == ~0ull) {
                if ((t & 63) == 0 && fb != 0xFFFFFFFFu) atomicAdd(&hist[fb], 64);
            } else if (bin != 0xFFFFFFFFu) {
                atomicAdd(&hist[bin], 1);
            }
        }
        __syncthreads();
        sc[t] = hist[t];
        __syncthreads();
        for (int off = 1; off < 256; off <<= 1) {
            int v = sc[t];
            if (t + off < 256) v += sc[t + off];
            __syncthreads();
            sc[t] = v;
            __syncthreads();
        }
        int gt = (t < 255) ? sc[t + 1] : 0;   // count of keys strictly above bin t
        if (gt < kk && kk <= gt + hist[t]) {
            s_prefix = (prefix << 8) | (unsigned)t;
            s_k = kk - gt;
        }
        __syncthreads();
    }
    if (t == 0) thr[row] = __uint_as_float(s_prefix);
}

// ---------------------------------------------------------------------------
// Kernel 3: collect candidates >= threshold with ONE atomic per block
// (block prefix-sum over per-thread match counts). ~99.4% of blocks exit
// after two scalar loads.
// ---------------------------------------------------------------------------
__global__ __launch_bounds__(256) void k_collect(
    const float* __restrict__ sp, const float* __restrict__ pp,
    const float* __restrict__ cmax, const float* __restrict__ thr,
    int* __restrict__ cnt, unsigned long long* __restrict__ cand, int cap)
{
    int c   = blockIdx.x;
    int row = c / NCHUNK;
    float tval = thr[row];
    if (cmax[c] < tval) return;   // block-uniform exit

    int cr = c - row * NCHUNK;
    long base = (long)row * ROW + (long)cr * CHUNK;
    int fr    = cr * CHUNK;
    int leaf0 = fr / VOCAB;
    int bnd   = (leaf0 + 1) * VOCAB;
    float p0  = pp[row * NLEAF + leaf0];
    float p1  = (leaf0 + 1 < NLEAF) ? pp[row * NLEAF + leaf0 + 1] : 0.f;

    int t = threadIdx.x;
    const float4* sp4 = (const float4*)(sp + base);
    float pr[16];
    int m = 0;
#pragma unroll
    for (int i = 0; i < 4; ++i) {
        int e4 = t + i * 256;
        float4 v = sp4[e4];
        float p = ((fr + e4 * 4) < bnd) ? p0 : p1;
        pr[i * 4 + 0] = v.x * p;
        pr[i * 4 + 1] = v.y * p;
        pr[i * 4 + 2] = v.z * p;
        pr[i * 4 + 3] = v.w * p;
#pragma unroll
        for (int j = 0; j < 4; ++j) m += (pr[i * 4 + j] >= tval) ? 1 : 0;
    }

    __shared__ int sc2[256];
    __shared__ int sbase;
    sc2[t] = m;
    __syncthreads();
    for (int off = 1; off < 256; off <<= 1) {       // inclusive Hillis-Steele
        int v = sc2[t];
        if (t >= off) v += sc2[t - off];
        __syncthreads();
        sc2[t] = v;
        __syncthreads();
    }
    if (t == 255) sbase = atomicAdd(&cnt[row], sc2[255]);
    __syncthreads();

    if (m > 0) {
        int pos = sbase + sc2[t] - m;
#pragma unroll
        for (int i = 0; i < 4; ++i) {
#pragma unroll
            for (int j = 0; j < 4; ++j) {
                float v = pr[i * 4 + j];
                if (v >= tval) {
                    if (pos < cap) {
                        unsigned fb = __float_as_uint(v);
                        unsigned fi = (unsigned)(fr + (t + i * 256) * 4 + j);
                        cand[(long)row * cap + pos] =
                            ((unsigned long long)fb << 32) |
                            (unsigned long long)(0xFFFFFFFFu - fi);
                    }
                    pos++;
                }
            }
        }
    }
}

// ---------------------------------------------------------------------------
// Kernel 4 (512 threads): per row, exact top-64 of the candidate keys.
// Fast path (nc <= 2048; measured nc ~= 1100): register-tiled rank-sort,
// jj-tiled by 8 so the 8 broadcast ds_read_b64 issue independently (latency
// hidden) before the 4x8 compare block (v_cmp_gt_u64). Each of 512 threads
// owns <=4 keys. Keys unique -> rank = #greater; ranks < 64 win.
// Fallback: 8-level radix select (strides updated for 512 threads).
// ---------------------------------------------------------------------------
__global__ __launch_bounds__(512) void k_final(
    const int* __restrict__ cnt, const unsigned long long* __restrict__ cand,
    int cap, float* __restrict__ out)
{
    int row = blockIdx.x;
    int t = threadIdx.x;
    int nc = cnt[row]; if (nc > cap) nc = cap;
    const unsigned long long* c = cand + (long)row * cap;

    if (nc <= 2048) {
        __shared__ unsigned long long keys[2048 + 8];
        for (int i = t; i < nc; i += 512) keys[i] = c[i];
        int ncp = (nc + 7) & ~7;               // pad to tile of 8
        for (int i = nc + t; i < ncp; i += 512) keys[i] = 0ull;  // 0 < any real key's rank effect
        __syncthreads();

        unsigned long long my[4];
        int rank[4];
#pragma unroll
        for (int q = 0; q < 4; ++q) {
            int i = t + q * 512;
            bool valid = (i < nc);
            my[q]   = valid ? keys[i] : ~0ull;  // ~0 never beaten -> rank stays TOPK
            rank[q] = valid ? 0 : TOPK;
        }
        for (int jj = 0; jj < ncp; jj += 8) {
            unsigned long long kt[8];
#pragma unroll
            for (int u = 0; u < 8; ++u) kt[u] = keys[jj + u];
#pragma unroll
            for (int u = 0; u < 8; ++u) {
#pragma unroll
                for (int q = 0; q < 4; ++q)
                    rank[q] += (kt[u] > my[q]) ? 1 : 0;
            }
        }
#pragma unroll
        for (int q = 0; q < 4; ++q) {
            if (rank[q] < TOPK) {
                unsigned long long k = my[q];
                unsigned fi = 0xFFFFFFFFu - (unsigned)(k & 0xFFFFFFFFull);
                float val = __uint_as_float((unsigned)(k >> 32));
                int tok  = (int)(fi % VOCAB);
                int leaf = (int)(fi / VOCAB);
                int r = rank[q];
                out[row * TOPK + r]                    = (float)tok;
                out[BATCH * TOPK + row * TOPK + r]     = val;
                out[2 * BATCH * TOPK + row * TOPK + r] = (float)leaf;
            }
        }
        return;
    }

    // ---- fallback: 8-level radix select over 64-bit keys (512 threads) ----
    __shared__ int hist[256], sc[256];
    __shared__ unsigned long long s_prefix;
    __shared__ int s_k;
    __shared__ unsigned long long stop[TOPK];
    __shared__ int s_ntop;
    if (t == 0) { s_prefix = 0ull; s_k = TOPK; s_ntop = 0; }
    __syncthreads();

    for (int level = 7; level >= 0; --level) {
        int shift = level * 8;
        if (t < 256) hist[t] = 0;
        __syncthreads();
        unsigned long long prefix = s_prefix; int kk = s_k;
        for (int i = t; i < nc; i += 512) {
            unsigned long long u = c[i];
            bool mm = (level == 7) || ((u >> (shift + 8)) == prefix);
            unsigned bin = mm ? (unsigned)((u >> shift) & 255ull) : 0xFFFFFFFFu;
            unsigned fb = __builtin_amdgcn_readfirstlane(bin);
            unsigned long long bal = __ballot(bin == fb);
            if (bal == ~0ull) {
                if ((t & 63) == 0 && fb != 0xFFFFFFFFu) atomicAdd(&hist[fb], 64);
            } else if (bin != 0xFFFFFFFFu) {
                atomicAdd(&hist[bin], 1);
            }
        }
        __syncthreads();
        if (t < 256) sc[t] = hist[t];
        __syncthreads();
        for (int off = 1; off < 256; off <<= 1) {
            int v = 0;
            if (t < 256) { v = sc[t]; if (t + off < 256) v += sc[t + off]; }
            __syncthreads();
            if (t < 256) sc[t] = v;
            __syncthreads();
        }
        if (t < 256) {
            int gt = (t < 255) ? sc[t + 1] : 0;
            if (gt < kk && kk <= gt + hist[t]) {
                s_prefix = (prefix << 8) | (unsigned long long)t;
                s_k = kk - gt;
            }
        }
        __syncthreads();
    }

    unsigned long long K64 = s_prefix;   // exact 64th-largest key
    for (int i = t; i < nc; i += 512) {
        unsigned long long u = c[i];
        if (u >= K64) {
            int p = atomicAdd(&s_ntop, 1);
            if (p < TOPK) stop[p] = u;
        }
    }
    __syncthreads();

    int ntop = s_ntop; if (ntop > TOPK) ntop = TOPK;
    if (t < ntop) {
        unsigned long long mykey = stop[t];
        int rank = 0;
        for (int j = 0; j < ntop; ++j) rank += (stop[j] > mykey) ? 1 : 0;
        unsigned fi = 0xFFFFFFFFu - (unsigned)(mykey & 0xFFFFFFFFull);
        float val = __uint_as_float((unsigned)(mykey >> 32));
        int tok  = (int)(fi % VOCAB);
        int leaf = (int)(fi / VOCAB);
        out[row * TOPK + rank]                    = (float)tok;
        out[BATCH * TOPK + row * TOPK + rank]     = val;
        out[2 * BATCH * TOPK + row * TOPK + rank] = (float)leaf;
    }
}

extern "C" void kernel_launch(void* const* d_in, const int* in_sizes, int n_in,
                              void* d_out, int out_size, void* d_ws, size_t ws_size,
                              hipStream_t stream) {
    const float* sp = (const float*)d_in[0];   // [8,64,128000] f32
    const float* pp = (const float*)d_in[1];   // [8,64] f32
    float* out = (float*)d_out;                // 1536 f32

    char* ws = (char*)d_ws;
    float* cmax = (float*)ws;                              // 16000 f32
    float* thr  = (float*)(ws + 64000);                    // 8 f32
    int*   cnt  = (int*)(ws + 64032);                      // 8 i32
    unsigned long long* cand = (unsigned long long*)(ws + 65536);

    int cap = 16384;
    size_t need = 65536 + (size_t)BATCH * (size_t)cap * 8;
    if (ws_size < need) {
        cap = (int)((ws_size > 65536 ? (ws_size - 65536) : 0) / (BATCH * 8));
        if (cap < 256) cap = 256;
    }

    k_chunkmax <<<BATCH * NCHUNK, 256, 0, stream>>>(sp, pp, cmax);
    k_threshold<<<BATCH,          256, 0, stream>>>(cmax, thr, cnt);
    k_collect  <<<BATCH * NCHUNK, 256, 0, stream>>>(sp, pp, cmax, thr, cnt, cand, cap);
    k_final    <<<BATCH,          512, 0, stream>>>(cnt, cand, cap, out);
}

// Round 6
// 400.256 us; speedup vs baseline: 1.4856x; 1.0871x over previous
//
#include <hip/hip_runtime.h>
#include <stdint.h>

#define BATCH 8
#define NLEAF 64
#define VOCAB 128000
#define ROW (NLEAF * VOCAB)        // 8,192,000
#define CHUNK 4096
#define NCHUNK (ROW / CHUNK)       // 2000 (exact)
#define TOPK 64
#define FBLK 8                     // k_final blocks per row (fast path)

// ---------------------------------------------------------------------------
// Kernel 1: per-chunk max of product. One block = one 4096-elem chunk.
// A chunk spans at most 2 leaves (CHUNK < VOCAB); VOCAB%4==0 so a float4
// never straddles a leaf boundary. This is the mandatory 262MB read.
// ---------------------------------------------------------------------------
__global__ __launch_bounds__(256) void k_chunkmax(
    const float* __restrict__ sp, const float* __restrict__ pp,
    float* __restrict__ cmax)
{
    int c   = blockIdx.x;            // 0 .. BATCH*NCHUNK-1
    int row = c / NCHUNK;
    int cr  = c - row * NCHUNK;
    long base = (long)row * ROW + (long)cr * CHUNK;
    int fr    = cr * CHUNK;          // row-local flat base
    int leaf0 = fr / VOCAB;
    int bnd   = (leaf0 + 1) * VOCAB; // row-local leaf boundary (multiple of 4)
    float p0  = pp[row * NLEAF + leaf0];
    float p1  = (leaf0 + 1 < NLEAF) ? pp[row * NLEAF + leaf0 + 1] : 0.f;

    int t = threadIdx.x;
    const float4* sp4 = (const float4*)(sp + base);
    float m = 0.f;                   // products are >= 0
#pragma unroll
    for (int i = 0; i < 4; ++i) {
        int e4 = t + i * 256;        // float4 index within chunk
        float4 v = sp4[e4];
        float p = ((fr + e4 * 4) < bnd) ? p0 : p1;
        m = fmaxf(m, fmaxf(fmaxf(v.x * p, v.y * p), fmaxf(v.z * p, v.w * p)));
    }
    for (int off = 32; off; off >>= 1) m = fmaxf(m, __shfl_down(m, off, 64));
    __shared__ float s[4];
    if ((t & 63) == 0) s[t >> 6] = m;
    __syncthreads();
    if (t == 0) cmax[c] = fmaxf(fmaxf(s[0], s[1]), fmaxf(s[2], s[3]));
}

// ---------------------------------------------------------------------------
// Kernel 2: per row, EXACT 64th-largest chunk max via 4-level radix select
// on the float bits (values >= 0 so uint order == float order).
// Also zeroes the candidate counter.
// ---------------------------------------------------------------------------
__global__ __launch_bounds__(256) void k_threshold(
    const float* __restrict__ cmax, float* __restrict__ thr,
    int* __restrict__ cnt)
{
    int row = blockIdx.x;
    int t = threadIdx.x;
    __shared__ unsigned uv[NCHUNK];
    __shared__ int hist[256], sc[256];
    __shared__ unsigned s_prefix;
    __shared__ int s_k;
    for (int i = t; i < NCHUNK; i += 256)
        uv[i] = __float_as_uint(cmax[row * NCHUNK + i]);
    if (t == 0) { cnt[row] = 0; s_prefix = 0u; s_k = TOPK; }
    __syncthreads();

    for (int level = 3; level >= 0; --level) {
        int shift = level * 8;
        hist[t] = 0;
        __syncthreads();
        unsigned prefix = s_prefix; int kk = s_k;
        for (int i = t; i < NCHUNK; i += 256) {
            unsigned u = uv[i];
            bool mm = (level == 3) || ((u >> (shift + 8)) == prefix);
            unsigned bin = mm ? ((u >> shift) & 255u) : 0xFFFFFFFFu;
            // wave-uniform fast path (degenerate levels: all keys same byte)
            unsigned fb = __builtin_amdgcn_readfirstlane(bin);
            unsigned long long bal = __ballot(bin == fb);
            if (bal == ~0ull) {
                if ((t & 63) == 0 && fb != 0xFFFFFFFFu) atomicAdd(&hist[fb], 64);
            } else if (bin != 0xFFFFFFFFu) {
                atomicAdd(&hist[bin], 1);
            }
        }
        __syncthreads();
        sc[t] = hist[t];
        __syncthreads();
        for (int off = 1; off < 256; off <<= 1) {
            int v = sc[t];
            if (t + off < 256) v += sc[t + off];
            __syncthreads();
            sc[t] = v;
            __syncthreads();
        }
        int gt = (t < 255) ? sc[t + 1] : 0;   // count of keys strictly above bin t
        if (gt < kk && kk <= gt + hist[t]) {
            s_prefix = (prefix << 8) | (unsigned)t;
            s_k = kk - gt;
        }
        __syncthreads();
    }
    if (t == 0) thr[row] = __uint_as_float(s_prefix);
}

// ---------------------------------------------------------------------------
// Kernel 3: collect candidates >= threshold with ONE atomic per block
// (block prefix-sum over per-thread match counts). ~99.4% of blocks exit
// after two scalar loads.
// ---------------------------------------------------------------------------
__global__ __launch_bounds__(256) void k_collect(
    const float* __restrict__ sp, const float* __restrict__ pp,
    const float* __restrict__ cmax, const float* __restrict__ thr,
    int* __restrict__ cnt, unsigned long long* __restrict__ cand, int cap)
{
    int c   = blockIdx.x;
    int row = c / NCHUNK;
    float tval = thr[row];
    if (cmax[c] < tval) return;   // block-uniform exit

    int cr = c - row * NCHUNK;
    long base = (long)row * ROW + (long)cr * CHUNK;
    int fr    = cr * CHUNK;
    int leaf0 = fr / VOCAB;
    int bnd   = (leaf0 + 1) * VOCAB;
    float p0  = pp[row * NLEAF + leaf0];
    float p1  = (leaf0 + 1 < NLEAF) ? pp[row * NLEAF + leaf0 + 1] : 0.f;

    int t = threadIdx.x;
    const float4* sp4 = (const float4*)(sp + base);
    float pr[16];
    int m = 0;
#pragma unroll
    for (int i = 0; i < 4; ++i) {
        int e4 = t + i * 256;
        float4 v = sp4[e4];
        float p = ((fr + e4 * 4) < bnd) ? p0 : p1;
        pr[i * 4 + 0] = v.x * p;
        pr[i * 4 + 1] = v.y * p;
        pr[i * 4 + 2] = v.z * p;
        pr[i * 4 + 3] = v.w * p;
#pragma unroll
        for (int j = 0; j < 4; ++j) m += (pr[i * 4 + j] >= tval) ? 1 : 0;
    }

    __shared__ int sc2[256];
    __shared__ int sbase;
    sc2[t] = m;
    __syncthreads();
    for (int off = 1; off < 256; off <<= 1) {       // inclusive Hillis-Steele
        int v = sc2[t];
        if (t >= off) v += sc2[t - off];
        __syncthreads();
        sc2[t] = v;
        __syncthreads();
    }
    if (t == 255) sbase = atomicAdd(&cnt[row], sc2[255]);
    __syncthreads();

    if (m > 0) {
        int pos = sbase + sc2[t] - m;
#pragma unroll
        for (int i = 0; i < 4; ++i) {
#pragma unroll
            for (int j = 0; j < 4; ++j) {
                float v = pr[i * 4 + j];
                if (v >= tval) {
                    if (pos < cap) {
                        unsigned fb = __float_as_uint(v);
                        unsigned fi = (unsigned)(fr + (t + i * 256) * 4 + j);
                        cand[(long)row * cap + pos] =
                            ((unsigned long long)fb << 32) |
                            (unsigned long long)(0xFFFFFFFFu - fi);
                    }
                    pos++;
                }
            }
        }
    }
}

// ---------------------------------------------------------------------------
// Kernel 4: per row, exact top-64 of the candidate keys.
// Fast path (nc <= 2048; measured nc ~= 1100): FBLK=8 blocks per row, each
// owns a 256-candidate slice (1 key/thread in a register). Block stages all
// keys to LDS, then each thread ranks its key vs the whole list in register
// tiles of 16 (broadcast ds_read_b64 batch, then independent cmp/add — no
// long serial chains, 64 CUs busy instead of 8).
// Keys unique -> rank = #greater; ranks < 64 win.
// Fallback (nc > 2048, never triggered on this data): proven 8-level radix
// select, run on block 0 of each row only.
// ---------------------------------------------------------------------------
__global__ __launch_bounds__(256) void k_final(
    const int* __restrict__ cnt, const unsigned long long* __restrict__ cand,
    int cap, float* __restrict__ out)
{
    int row = blockIdx.x / FBLK;
    int blk = blockIdx.x - row * FBLK;
    int t = threadIdx.x;
    int nc = cnt[row]; if (nc > cap) nc = cap;
    const unsigned long long* c = cand + (long)row * cap;

    if (nc <= 2048) {
        if (blk * 256 >= nc) return;           // slice empty, block-uniform
        __shared__ unsigned long long keys[2048 + 16];
        for (int i = t; i < nc; i += 256) keys[i] = c[i];
        int ncp = (nc + 15) & ~15;             // pad to tile of 16
        for (int i = nc + t; i < ncp; i += 256) keys[i] = 0ull;  // 0 < any real key
        __syncthreads();

        int i = blk * 256 + t;
        unsigned long long my = (i < nc) ? keys[i] : ~0ull;
        int rank = (i < nc) ? 0 : TOPK;
        for (int jj = 0; jj < ncp; jj += 16) {
            unsigned long long kt[16];
#pragma unroll
            for (int u = 0; u < 16; ++u) kt[u] = keys[jj + u];
#pragma unroll
            for (int u = 0; u < 16; ++u) rank += (kt[u] > my) ? 1 : 0;
        }
        if (rank < TOPK) {
            unsigned fi = 0xFFFFFFFFu - (unsigned)(my & 0xFFFFFFFFull);
            float val = __uint_as_float((unsigned)(my >> 32));
            int tok  = (int)(fi % VOCAB);
            int leaf = (int)(fi / VOCAB);
            out[row * TOPK + rank]                    = (float)tok;
            out[BATCH * TOPK + row * TOPK + rank]     = val;
            out[2 * BATCH * TOPK + row * TOPK + rank] = (float)leaf;
        }
        return;
    }

    // ---- fallback: 8-level radix select over 64-bit keys (block 0 only) ----
    if (blk != 0) return;
    __shared__ int hist[256], sc[256];
    __shared__ unsigned long long s_prefix;
    __shared__ int s_k;
    __shared__ unsigned long long stop[TOPK];
    __shared__ int s_ntop;
    if (t == 0) { s_prefix = 0ull; s_k = TOPK; s_ntop = 0; }
    __syncthreads();

    for (int level = 7; level >= 0; --level) {
        int shift = level * 8;
        hist[t] = 0;
        __syncthreads();
        unsigned long long prefix = s_prefix; int kk = s_k;
        for (int i = t; i < nc; i += 256) {
            unsigned long long u = c[i];
            bool mm = (level == 7) || ((u >> (shift + 8)) == prefix);
            unsigned bin = mm ? (unsigned)((u >> shift) & 255ull) : 0xFFFFFFFFu;
            unsigned fb = __builtin_amdgcn_readfirstlane(bin);
            unsigned long long bal = __ballot(bin == fb);
            if (bal == ~0ull) {
                if ((t & 63) == 0 && fb != 0xFFFFFFFFu) atomicAdd(&hist[fb], 64);
            } else if (bin != 0xFFFFFFFFu) {
                atomicAdd(&hist[bin], 1);
            }
        }
        __syncthreads();
        sc[t] = hist[t];
        __syncthreads();
        for (int off = 1; off < 256; off <<= 1) {
            int v = sc[t];
            if (t + off < 256) v += sc[t + off];
            __syncthreads();
            sc[t] = v;
            __syncthreads();
        }
        int gt = (t < 255) ? sc[t + 1] : 0;
        if (gt < kk && kk <= gt + hist[t]) {
            s_prefix = (prefix << 8) | (unsigned long long)t;
            s_k = kk - gt;
        }
        __syncthreads();
    }

    unsigned long long K64 = s_prefix;   // exact 64th-largest key
    for (int i = t; i < nc; i += 256) {
        unsigned long long u = c[i];
        if (u >= K64) {
            int p = atomicAdd(&s_ntop, 1);
            if (p < TOPK) stop[p] = u;
        }
    }
    __syncthreads();

    int ntop = s_ntop; if (ntop > TOPK) ntop = TOPK;
    if (t < ntop) {
        unsigned long long mykey = stop[t];
        int rank = 0;
        for (int j = 0; j < ntop; ++j) rank += (stop[j] > mykey) ? 1 : 0;
        unsigned fi = 0xFFFFFFFFu - (unsigned)(mykey & 0xFFFFFFFFull);
        float val = __uint_as_float((unsigned)(mykey >> 32));
        int tok  = (int)(fi % VOCAB);
        int leaf = (int)(fi / VOCAB);
        out[row * TOPK + rank]                    = (float)tok;
        out[BATCH * TOPK + row * TOPK + rank]     = val;
        out[2 * BATCH * TOPK + row * TOPK + rank] = (float)leaf;
    }
}

extern "C" void kernel_launch(void* const* d_in, const int* in_sizes, int n_in,
                              void* d_out, int out_size, void* d_ws, size_t ws_size,
                              hipStream_t stream) {
    const float* sp = (const float*)d_in[0];   // [8,64,128000] f32
    const float* pp = (const float*)d_in[1];   // [8,64] f32
    float* out = (float*)d_out;                // 1536 f32

    char* ws = (char*)d_ws;
    float* cmax = (float*)ws;                              // 16000 f32
    float* thr  = (float*)(ws + 64000);                    // 8 f32
    int*   cnt  = (int*)(ws + 64032);                      // 8 i32
    unsigned long long* cand = (unsigned long long*)(ws + 65536);

    int cap = 16384;
    size_t need = 65536 + (size_t)BATCH * (size_t)cap * 8;
    if (ws_size < need) {
        cap = (int)((ws_size > 65536 ? (ws_size - 65536) : 0) / (BATCH * 8));
        if (cap < 256) cap = 256;
    }

    k_chunkmax <<<BATCH * NCHUNK, 256, 0, stream>>>(sp, pp, cmax);
    k_threshold<<<BATCH,          256, 0, stream>>>(cmax, thr, cnt);
    k_collect  <<<BATCH * NCHUNK, 256, 0, stream>>>(sp, pp, cmax, thr, cnt, cand, cap);
    k_final    <<<BATCH * FBLK,   256, 0, stream>>>(cnt, cand, cap, out);
}